// Round 1
// baseline (3802.695 us; speedup 1.0000x reference)
//
#include <hip/hip_runtime.h>
#include <hip/hip_bf16.h>

#define N_NODES 20000
#define N_EDGES 320000
#define DIM 300
#define N_LAYERS 5
#define VOCAB 119
#define EDIM 7
#define NGRAPH 128
#define NCLS 6
#define DHALF 150
#define BN_EPS 1e-5f

#define CDIV(a, b) (((a) + (b) - 1) / (b))

// ---------------- node encoder: h[n][d] = node_emb[x[n]][d] ----------------
__global__ void node_enc_kernel(const int* __restrict__ x,
                                const float* __restrict__ node_emb,
                                float* __restrict__ h) {
    int idx = blockIdx.x * blockDim.x + threadIdx.x;
    if (idx >= N_NODES * DIM) return;
    int n = idx / DIM;
    int d = idx - n * DIM;
    h[idx] = node_emb[x[n] * DIM + d];
}

// ---------------- message + scatter-add (edge encoder fused) ----------------
// wave per edge; lanes along D. ea computed on the fly from edge_attr (K=7).
__global__ void msg_kernel(const float* __restrict__ h,
                           float* __restrict__ agg,
                           const int* __restrict__ src,
                           const int* __restrict__ dst,
                           const float* __restrict__ edge_attr,
                           const float* __restrict__ edge_W,
                           const float* __restrict__ edge_b) {
    int gtid = blockIdx.x * blockDim.x + threadIdx.x;
    int wave = gtid >> 6;
    int lane = threadIdx.x & 63;
    int nwaves = (gridDim.x * blockDim.x) >> 6;
    for (int e = wave; e < N_EDGES; e += nwaves) {
        int s = src[e];
        int t = dst[e];
        const float* ar = edge_attr + e * EDIM;
        float a0 = ar[0], a1 = ar[1], a2 = ar[2], a3 = ar[3];
        float a4 = ar[4], a5 = ar[5], a6 = ar[6];
        const float* hrow = h + s * DIM;
        float* grow = agg + t * DIM;
#pragma unroll
        for (int c = 0; c < 5; ++c) {
            int d = lane + (c << 6);
            if (d < DIM) {
                float ea = edge_b[d];
                ea += a0 * edge_W[0 * DIM + d];
                ea += a1 * edge_W[1 * DIM + d];
                ea += a2 * edge_W[2 * DIM + d];
                ea += a3 * edge_W[3 * DIM + d];
                ea += a4 * edge_W[4 * DIM + d];
                ea += a5 * edge_W[5 * DIM + d];
                ea += a6 * edge_W[6 * DIM + d];
                float m = hrow[d] + ea;
                if (m > 0.0f) atomicAdd(&grow[d], m);  // relu: skip zeros
            }
        }
    }
}

// ---------------- z = (1+eps)*h + agg ----------------
__global__ void zcomb_kernel(const float* __restrict__ h,
                             const float* __restrict__ agg,
                             const float* __restrict__ eps, int layer,
                             float* __restrict__ z) {
    int idx = blockIdx.x * blockDim.x + threadIdx.x;
    if (idx >= N_NODES * DIM) return;
    float e = eps[layer];
    z[idx] = (1.0f + e) * h[idx] + agg[idx];
}

// ---------------- tiled fp32 GEMM: C[n][m] = f(A[n][k]) * W[k][m] + bias[m] ---
// block tile 128x64, 256 threads, thread tile 8x4. K = M = 300.
// BNA: A element transformed as relu(a*scale[k]+shift[k]) on load.
template <bool BNA>
__global__ __launch_bounds__(256) void gemm_kernel(
    const float* __restrict__ A, const float* __restrict__ W,
    const float* __restrict__ bias, const float* __restrict__ scale,
    const float* __restrict__ shift, float* __restrict__ C) {
    __shared__ float sA[16][129];  // transposed: sA[k][row], pad -> conflict-lite
    __shared__ float sB[16][64];

    int tid = threadIdx.x;
    int tx = tid & 15;        // col group
    int ty = tid >> 4;        // row group
    int row0 = blockIdx.x * 128;
    int col0 = blockIdx.y * 64;

    float acc[8][4];
#pragma unroll
    for (int r = 0; r < 8; ++r)
#pragma unroll
        for (int c = 0; c < 4; ++c) acc[r][c] = 0.0f;

    int la_k = tid & 15;   // k within tile
    int la_r = tid >> 4;   // row base

    for (int kt = 0; kt < 19; ++kt) {
        int k0 = kt * 16;
        // load A tile (128 x 16), transposed into sA
#pragma unroll
        for (int it = 0; it < 8; ++it) {
            int r = la_r + it * 16;
            int grow = row0 + r;
            int gk = k0 + la_k;
            float v = 0.0f;
            if (grow < N_NODES && gk < DIM) {
                v = A[grow * DIM + gk];
                if (BNA) v = fmaxf(v * scale[gk] + shift[gk], 0.0f);
            }
            sA[la_k][r] = v;
        }
        // load B tile (16 x 64)
#pragma unroll
        for (int it = 0; it < 4; ++it) {
            int lin = tid + it * 256;
            int k = lin >> 6;
            int c = lin & 63;
            int gk = k0 + k;
            int gc = col0 + c;
            sB[k][c] = (gk < DIM && gc < DIM) ? W[gk * DIM + gc] : 0.0f;
        }
        __syncthreads();
#pragma unroll
        for (int k = 0; k < 16; ++k) {
            float a[8], b[4];
#pragma unroll
            for (int r = 0; r < 8; ++r) a[r] = sA[k][ty * 8 + r];
#pragma unroll
            for (int c = 0; c < 4; ++c) b[c] = sB[k][tx * 4 + c];
#pragma unroll
            for (int r = 0; r < 8; ++r)
#pragma unroll
                for (int c = 0; c < 4; ++c) acc[r][c] += a[r] * b[c];
        }
        __syncthreads();
    }
#pragma unroll
    for (int r = 0; r < 8; ++r) {
        int grow = row0 + ty * 8 + r;
        if (grow >= N_NODES) continue;
#pragma unroll
        for (int c = 0; c < 4; ++c) {
            int gc = col0 + tx * 4 + c;
            if (gc < DIM) C[grow * DIM + gc] = acc[r][c] + bias[gc];
        }
    }
}

// ---------------- column stats: sum, sumsq over rows ----------------
#define STAT_BLOCKS 125
#define STAT_ROWS 160
__global__ void stats_kernel(const float* __restrict__ y,
                             float* __restrict__ s1, float* __restrict__ s2) {
    int tid = threadIdx.x;  // 256
    int r0 = blockIdx.x * STAT_ROWS;
    float a1 = 0.f, q1 = 0.f, a2 = 0.f, q2 = 0.f;
    for (int r = r0; r < r0 + STAT_ROWS; ++r) {
        float v = y[r * DIM + tid];
        a1 += v; q1 += v * v;
        if (tid < DIM - 256) {
            float w = y[r * DIM + 256 + tid];
            a2 += w; q2 += w * w;
        }
    }
    atomicAdd(&s1[tid], a1);
    atomicAdd(&s2[tid], q1);
    if (tid < DIM - 256) {
        atomicAdd(&s1[256 + tid], a2);
        atomicAdd(&s2[256 + tid], q2);
    }
}

// ---------------- scale/shift from stats ----------------
__global__ void scaleshift_kernel(const float* __restrict__ s1,
                                  const float* __restrict__ s2,
                                  const float* __restrict__ g,
                                  const float* __restrict__ be,
                                  float* __restrict__ scale,
                                  float* __restrict__ shift) {
    int d = blockIdx.x * blockDim.x + threadIdx.x;
    if (d >= DIM) return;
    const float invn = 1.0f / (float)N_NODES;
    float mean = s1[d] * invn;
    float var = s2[d] * invn - mean * mean;
    float sc = g[d] * rsqrtf(var + BN_EPS);
    scale[d] = sc;
    shift[d] = be[d] - mean * sc;
}

// ---------------- h = relu(y*scale + shift) ----------------
__global__ void apply_bn_kernel(const float* __restrict__ y,
                                const float* __restrict__ scale,
                                const float* __restrict__ shift,
                                float* __restrict__ h) {
    int idx = blockIdx.x * blockDim.x + threadIdx.x;
    if (idx >= N_NODES * DIM) return;
    int d = idx % DIM;
    h[idx] = fmaxf(y[idx] * scale[d] + shift[d], 0.0f);
}

// ---------------- pooling: atomics into pooled[g][d], counts[g] ----------------
__global__ void pool_kernel(const float* __restrict__ h,
                            const int* __restrict__ batch,
                            float* __restrict__ pooled,
                            float* __restrict__ counts) {
    int n = blockIdx.x;
    int tid = threadIdx.x;  // 256
    int g = batch[n];
    if (tid == 0) atomicAdd(&counts[g], 1.0f);
    const float* hrow = h + n * DIM;
    float* prow = pooled + g * DIM;
    atomicAdd(&prow[tid], hrow[tid]);
    if (tid < DIM - 256) atomicAdd(&prow[256 + tid], hrow[256 + tid]);
}

// ---------------- MLP head ----------------
__global__ void mlp1_kernel(const float* __restrict__ pooled,
                            const float* __restrict__ counts,
                            const float* __restrict__ Wc1,
                            const float* __restrict__ bc1,
                            float* __restrict__ hidden) {
    int g = blockIdx.x;
    int j = threadIdx.x;  // 192 threads
    if (j >= DHALF) return;
    float inv = 1.0f / fmaxf(counts[g], 1.0f);
    const float* prow = pooled + g * DIM;
    float acc = 0.0f;
    for (int k = 0; k < DIM; ++k) acc += prow[k] * Wc1[k * DHALF + j];
    hidden[g * DHALF + j] = fmaxf(acc * inv + bc1[j], 0.0f);
}

__global__ void mlp2_kernel(const float* __restrict__ hidden,
                            const float* __restrict__ Wc2,
                            const float* __restrict__ bc2,
                            float* __restrict__ out) {
    int idx = blockIdx.x * blockDim.x + threadIdx.x;
    if (idx >= NGRAPH * NCLS) return;
    int g = idx / NCLS;
    int c = idx - g * NCLS;
    const float* hrow = hidden + g * DHALF;
    float acc = bc2[c];
    for (int j = 0; j < DHALF; ++j) acc += hrow[j] * Wc2[j * NCLS + c];
    out[idx] = acc;
}

extern "C" void kernel_launch(void* const* d_in, const int* in_sizes, int n_in,
                              void* d_out, int out_size, void* d_ws, size_t ws_size,
                              hipStream_t stream) {
    const int*   x         = (const int*)d_in[0];
    const int*   edge_index= (const int*)d_in[1];
    const float* edge_attr = (const float*)d_in[2];
    const int*   batch     = (const int*)d_in[3];
    const float* node_emb  = (const float*)d_in[4];
    const float* edge_W    = (const float*)d_in[5];
    const float* edge_b    = (const float*)d_in[6];
    const float* eps       = (const float*)d_in[7];
    const float* W1        = (const float*)d_in[8];
    const float* b1        = (const float*)d_in[9];
    const float* g1        = (const float*)d_in[10];
    const float* be1       = (const float*)d_in[11];
    const float* W2        = (const float*)d_in[12];
    const float* b2        = (const float*)d_in[13];
    const float* g2        = (const float*)d_in[14];
    const float* be2       = (const float*)d_in[15];
    const float* Wc1       = (const float*)d_in[16];
    const float* bc1       = (const float*)d_in[17];
    const float* Wc2       = (const float*)d_in[18];
    const float* bc2       = (const float*)d_in[19];
    float* out = (float*)d_out;

    const int* src = edge_index;            // edge_index[0] = x_j (message source)
    const int* dst = edge_index + N_EDGES;  // edge_index[1] = aggregation target

    const size_t ND = (size_t)N_NODES * DIM;  // 6,000,000
    float* ws = (float*)d_ws;
    float* h  = ws;             // [N,D]
    float* B1 = h + ND;         // agg / y1
    float* B2 = B1 + ND;        // z / y2
    float* sm = B2 + ND;        // small region
    float* colsum = sm;         // 300 (pad to 320)
    float* colsq  = sm + 320;   // 300
    float* scale  = sm + 640;   // 300
    float* shift  = sm + 960;   // 300
    float* pooled = sm + 1280;          // 128*300
    float* counts = pooled + NGRAPH * DIM;  // 128
    float* hidden = counts + NGRAPH;        // 128*150

    const int EW_BLOCKS = CDIV((int)ND, 256);  // elementwise grid

    // h = node_emb[x]
    node_enc_kernel<<<EW_BLOCKS, 256, 0, stream>>>(x, node_emb, h);

    dim3 ggrid(CDIV(N_NODES, 128), CDIV(DIM, 64));  // 157 x 5

    for (int i = 0; i < N_LAYERS; ++i) {
        // agg = 0
        hipMemsetAsync(B1, 0, ND * sizeof(float), stream);
        // message + scatter
        msg_kernel<<<1024, 256, 0, stream>>>(h, B1, src, dst, edge_attr, edge_W, edge_b);
        // z = (1+eps)*h + agg
        zcomb_kernel<<<EW_BLOCKS, 256, 0, stream>>>(h, B1, eps, i, B2);
        // y1 = z @ W1 + b1   (B2 -> B1)
        gemm_kernel<false><<<ggrid, 256, 0, stream>>>(B2, W1 + i * DIM * DIM,
                                                      b1 + i * DIM, nullptr, nullptr, B1);
        // BN1 stats
        hipMemsetAsync(colsum, 0, 640 * sizeof(float), stream);
        stats_kernel<<<STAT_BLOCKS, 256, 0, stream>>>(B1, colsum, colsq);
        scaleshift_kernel<<<2, 256, 0, stream>>>(colsum, colsq, g1 + i * DIM,
                                                 be1 + i * DIM, scale, shift);
        // y2 = relu(BN(y1)) @ W2 + b2   (B1 -> B2)
        gemm_kernel<true><<<ggrid, 256, 0, stream>>>(B1, W2 + i * DIM * DIM,
                                                     b2 + i * DIM, scale, shift, B2);
        // BN2 stats
        hipMemsetAsync(colsum, 0, 640 * sizeof(float), stream);
        stats_kernel<<<STAT_BLOCKS, 256, 0, stream>>>(B2, colsum, colsq);
        scaleshift_kernel<<<2, 256, 0, stream>>>(colsum, colsq, g2 + i * DIM,
                                                 be2 + i * DIM, scale, shift);
        // h = relu(BN(y2))
        apply_bn_kernel<<<EW_BLOCKS, 256, 0, stream>>>(B2, scale, shift, h);
    }

    // pooling
    hipMemsetAsync(pooled, 0, (NGRAPH * DIM + NGRAPH) * sizeof(float), stream);
    pool_kernel<<<N_NODES, 256, 0, stream>>>(h, batch, pooled, counts);
    // head
    mlp1_kernel<<<NGRAPH, 192, 0, stream>>>(pooled, counts, Wc1, bc1, hidden);
    mlp2_kernel<<<CDIV(NGRAPH * NCLS, 256), 256, 0, stream>>>(hidden, Wc2, bc2, out);
}

// Round 2
// 1397.302 us; speedup vs baseline: 2.7215x; 2.7215x over previous
//
#include <hip/hip_runtime.h>
#include <hip/hip_bf16.h>
#include <stdint.h>

#define N_NODES 20000
#define N_EDGES 320000
#define DIM 300
#define ADIM 320              // padded activation stride (cols 300..319 = 0)
#define ROWS_PAD 20032        // 313 * 64
#define N_LAYERS 5
#define EDIM 7
#define NGRAPH 128
#define NCLS 6
#define DHALF 150
#define BN_EPS 1e-5f

#define CDIV(a, b) (((a) + (b) - 1) / (b))

typedef short bf16x8 __attribute__((ext_vector_type(8)));
typedef float f32x4 __attribute__((ext_vector_type(4)));
typedef unsigned short ushort_t;

__device__ __forceinline__ float bf2f(ushort_t u) {
    union { float f; uint32_t i; } v; v.i = ((uint32_t)u) << 16; return v.f;
}
__device__ __forceinline__ ushort_t f2bf(float f) {
    union { float f; uint32_t i; } v; v.f = f;
    uint32_t x = v.i;
    x += 0x7FFFu + ((x >> 16) & 1u);   // RTN-even (no inf/nan expected)
    return (ushort_t)(x >> 16);
}

// ---------------- node encoder: h_bf[n][d] = bf16(node_emb[x[n]][d]) --------
__global__ void node_enc_kernel(const int* __restrict__ x,
                                const float* __restrict__ node_emb,
                                ushort_t* __restrict__ h_bf) {
    int idx = blockIdx.x * blockDim.x + threadIdx.x;  // 20000*40
    if (idx >= N_NODES * 40) return;
    int n = idx / 40;
    int d0 = (idx - n * 40) * 8;
    const float* src = node_emb + (size_t)x[n] * DIM;
    union { ushort_t u[8]; uint4 v; } o;
#pragma unroll
    for (int j = 0; j < 8; ++j) {
        int d = d0 + j;
        o.u[j] = (d < DIM) ? f2bf(src[d]) : (ushort_t)0;
    }
    *(uint4*)(h_bf + (size_t)n * ADIM + d0) = o.v;
}

// ---------------- W transpose+convert: Wt[mat][n][k] = bf16(W[k][n]) --------
__global__ void wt_prep_kernel(const float* __restrict__ W1,
                               const float* __restrict__ W2,
                               ushort_t* __restrict__ Wt) {
    int idx = blockIdx.x * blockDim.x + threadIdx.x;  // 10*320*320
    if (idx >= 10 * ADIM * ADIM) return;
    int mat = idx / (ADIM * ADIM);
    int rem = idx - mat * ADIM * ADIM;
    int k = rem / ADIM;
    int n = rem - k * ADIM;
    const float* src = (mat < 5) ? (W1 + (size_t)mat * DIM * DIM)
                                 : (W2 + (size_t)(mat - 5) * DIM * DIM);
    float v = (k < DIM && n < DIM) ? src[(size_t)k * DIM + n] : 0.0f;
    Wt[(size_t)mat * ADIM * ADIM + (size_t)n * ADIM + k] = f2bf(v);
}

// ---------------- CSR build ----------------
__global__ void deg_kernel(const int* __restrict__ dst, int* __restrict__ deg) {
    int e = blockIdx.x * blockDim.x + threadIdx.x;
    if (e < N_EDGES) atomicAdd(&deg[dst[e]], 1);
}

__global__ void scan_kernel(const int* __restrict__ deg, int* __restrict__ off,
                            int* __restrict__ cur) {
    __shared__ int sh[1024];
    int t = threadIdx.x;
    int base = t * 20;
    int local[20];
    int s = 0;
#pragma unroll
    for (int j = 0; j < 20; ++j) {
        int i = base + j;
        int v = (i < N_NODES) ? deg[i] : 0;
        local[j] = v;
        s += v;
    }
    sh[t] = s;
    __syncthreads();
    for (int o = 1; o < 1024; o <<= 1) {
        int v = sh[t];
        int add = (t >= o) ? sh[t - o] : 0;
        __syncthreads();
        sh[t] = v + add;
        __syncthreads();
    }
    int run = (t > 0) ? sh[t - 1] : 0;
#pragma unroll
    for (int j = 0; j < 20; ++j) {
        int i = base + j;
        if (i < N_NODES) {
            off[i] = run;
            cur[i] = run;
            run += local[j];
        }
    }
    if (t == 1023) off[N_NODES] = sh[1023];
}

__global__ void scatter_kernel(const int* __restrict__ src,
                               const int* __restrict__ dst,
                               const float* __restrict__ edge_attr,
                               int* __restrict__ cur,
                               int* __restrict__ perm_src,
                               float* __restrict__ perm_ea) {
    int e = blockIdx.x * blockDim.x + threadIdx.x;
    if (e >= N_EDGES) return;
    int d = dst[e];
    int p = atomicAdd(&cur[d], 1);
    perm_src[p] = src[e];
    const float* ar = edge_attr + (size_t)e * EDIM;
    float* pr = perm_ea + (size_t)p * 8;
#pragma unroll
    for (int j = 0; j < EDIM; ++j) pr[j] = ar[j];
    pr[7] = 0.0f;
}

// ---------------- CSR message+aggregate+combine: z_bf = (1+eps)*h + agg ------
#define MSG_BLOCKS 768
#define MSG_WAVES (MSG_BLOCKS * 4)
__global__ __launch_bounds__(256) void msg_kernel(
    const ushort_t* __restrict__ h_bf, ushort_t* __restrict__ z_bf,
    const int* __restrict__ off, const int* __restrict__ perm_src,
    const float* __restrict__ perm_ea, const float* __restrict__ edge_W,
    const float* __restrict__ edge_b, const float* __restrict__ eps, int layer) {
    int gw = (blockIdx.x * 256 + threadIdx.x) >> 6;
    int lane = threadIdx.x & 63;

    // hoist edge encoder weights for this lane's 5 d-slots (zeros for d>=300)
    float ew[5][7], eb[5];
#pragma unroll
    for (int c = 0; c < 5; ++c) {
        int d = c * 64 + lane;
        bool ok = (d < DIM);
        eb[c] = ok ? edge_b[d] : 0.0f;
#pragma unroll
        for (int j = 0; j < EDIM; ++j)
            ew[c][j] = ok ? edge_W[j * DIM + d] : 0.0f;
    }
    float epsv = 1.0f + eps[layer];

    for (int n = gw; n < N_NODES; n += MSG_WAVES) {
        int p0 = off[n], p1 = off[n + 1];
        float acc[5] = {0.f, 0.f, 0.f, 0.f, 0.f};
        for (int p = p0; p < p1; ++p) {
            int s = perm_src[p];
            const float* ap = perm_ea + (size_t)p * 8;
            float4 a03 = *(const float4*)ap;
            float4 a47 = *(const float4*)(ap + 4);
            const ushort_t* hr = h_bf + (size_t)s * ADIM;
#pragma unroll
            for (int c = 0; c < 5; ++c) {
                int d = c * 64 + lane;
                float hv = bf2f(hr[d]);  // 0 for d>=300
                float ea = eb[c];
                ea += a03.x * ew[c][0];
                ea += a03.y * ew[c][1];
                ea += a03.z * ew[c][2];
                ea += a03.w * ew[c][3];
                ea += a47.x * ew[c][4];
                ea += a47.y * ew[c][5];
                ea += a47.z * ew[c][6];
                float m = hv + ea;       // for d>=300: 0+0 -> relu 0
                acc[c] += fmaxf(m, 0.0f);
            }
        }
        const ushort_t* hn = h_bf + (size_t)n * ADIM;
        ushort_t* zr = z_bf + (size_t)n * ADIM;
#pragma unroll
        for (int c = 0; c < 5; ++c) {
            int d = c * 64 + lane;
            float z = epsv * bf2f(hn[d]) + acc[c];
            zr[d] = f2bf(z);             // d>=300 -> 0
        }
    }
}

// ---------------- bf16 MFMA GEMM: Y[n][m] = A[n][:] . W[:][m] ----------------
// A: [ROWS_PAD][320] bf16 (pad rows/cols zero). Wt: [320][320] bf16, Wt[n][k].
// Y: [*][320] f32, only rows<20000, cols<300 written.
// Block: 64 rows x 160 cols, 256 thr = 4 waves (2M x 2N), wave tile 32x80.
#define GBM 64
#define GBN 160
__device__ __forceinline__ int swz(int row, int k8) {
    return ((row << 6) + (k8 << 4)) ^ ((row & 7) << 4);
}

__global__ __launch_bounds__(256) void gemm_kernel(
    const ushort_t* __restrict__ A, const ushort_t* __restrict__ Wt,
    float* __restrict__ Y) {
    __shared__ ushort_t sA[GBM * 32];   // 4 KB, swizzled
    __shared__ ushort_t sB[GBN * 32];   // 10 KB, swizzled
    char* sAc = (char*)sA;
    char* sBc = (char*)sB;

    int tid = threadIdx.x;
    int lane = tid & 63;
    int wv = tid >> 6;
    int wm = wv & 1;        // 0..1 -> 32-row half
    int wn = wv >> 1;       // 0..1 -> 80-col half
    int brow = blockIdx.x * GBM;
    int bcol = blockIdx.y * GBN;

    f32x4 acc[2][5];
#pragma unroll
    for (int m = 0; m < 2; ++m)
#pragma unroll
        for (int n = 0; n < 5; ++n) acc[m][n] = (f32x4){0.f, 0.f, 0.f, 0.f};

    int arow = tid >> 2;          // 0..63
    int ak8 = tid & 3;            // 16B chunk in K
    const int alds = swz(arow, ak8);

    for (int kt = 0; kt < 10; ++kt) {
        int k0 = kt * 32;
        // stage A: 64x32 bf16 -> one uint4 per thread
        {
            const ushort_t* g = A + (size_t)(brow + arow) * ADIM + k0 + ak8 * 8;
            *(uint4*)(sAc + alds) = *(const uint4*)g;
        }
        // stage B: 160x32 bf16 -> 640 chunks
#pragma unroll
        for (int it = 0; it < 3; ++it) {
            int idx = tid + it * 256;
            if (idx < 640) {
                int row = idx >> 2, k8 = idx & 3;
                const ushort_t* g = Wt + (size_t)(bcol + row) * ADIM + k0 + k8 * 8;
                *(uint4*)(sBc + swz(row, k8)) = *(const uint4*)g;
            }
        }
        __syncthreads();

        bf16x8 a[2], b[5];
        int l15 = lane & 15, l4 = lane >> 4;
#pragma unroll
        for (int m = 0; m < 2; ++m) {
            int row = wm * 32 + m * 16 + l15;
            a[m] = *(const bf16x8*)(sAc + swz(row, l4));
        }
#pragma unroll
        for (int n = 0; n < 5; ++n) {
            int row = wn * 80 + n * 16 + l15;
            b[n] = *(const bf16x8*)(sBc + swz(row, l4));
        }
#pragma unroll
        for (int m = 0; m < 2; ++m)
#pragma unroll
            for (int n = 0; n < 5; ++n)
                acc[m][n] = __builtin_amdgcn_mfma_f32_16x16x32_bf16(
                    a[m], b[n], acc[m][n], 0, 0, 0);
        __syncthreads();
    }

    int l15 = lane & 15, l4 = lane >> 4;
#pragma unroll
    for (int m = 0; m < 2; ++m) {
#pragma unroll
        for (int n = 0; n < 5; ++n) {
            int col = bcol + wn * 80 + n * 16 + l15;
            if (col >= DIM) continue;
#pragma unroll
            for (int r = 0; r < 4; ++r) {
                int row = brow + wm * 32 + m * 16 + l4 * 4 + r;
                if (row < N_NODES) Y[(size_t)row * ADIM + col] = acc[m][n][r];
            }
        }
    }
}

// ---------------- column stats over Y (stride 320, cols<300) ----------------
#define STAT_BLOCKS 125
#define STAT_ROWS 160
__global__ void stats_kernel(const float* __restrict__ y,
                             float* __restrict__ s1, float* __restrict__ s2) {
    int d = threadIdx.x;  // 320
    if (d >= DIM) return;
    int r0 = blockIdx.x * STAT_ROWS;
    float a = 0.f, q = 0.f;
    for (int r = r0; r < r0 + STAT_ROWS; ++r) {
        float v = y[(size_t)r * ADIM + d];
        a += v; q += v * v;
    }
    atomicAdd(&s1[d], a);
    atomicAdd(&s2[d], q);
}

__global__ void scaleshift_kernel(const float* __restrict__ s1,
                                  const float* __restrict__ s2,
                                  const float* __restrict__ g,
                                  const float* __restrict__ be,
                                  float* __restrict__ scale,
                                  float* __restrict__ shift) {
    int d = blockIdx.x * blockDim.x + threadIdx.x;
    if (d >= DIM) return;
    const float invn = 1.0f / (float)N_NODES;
    float mean = s1[d] * invn;
    float var = s2[d] * invn - mean * mean;
    float sc = g[d] * rsqrtf(var + BN_EPS);
    scale[d] = sc;
    shift[d] = be[d] - mean * sc;
}

// ---------------- out_bf = bf16(relu(y*scale+shift)), cols>=300 -> 0 --------
__global__ void apply_bn_kernel(const float* __restrict__ y,
                                const float* __restrict__ scale,
                                const float* __restrict__ shift,
                                ushort_t* __restrict__ out_bf) {
    int idx = blockIdx.x * blockDim.x + threadIdx.x;  // 20000*40
    if (idx >= N_NODES * 40) return;
    int n = idx / 40;
    int d0 = (idx - n * 40) * 8;
    const float* yr = y + (size_t)n * ADIM + d0;
    union { ushort_t u[8]; uint4 v; } o;
#pragma unroll
    for (int j = 0; j < 8; ++j) {
        int d = d0 + j;
        float r = 0.0f;
        if (d < DIM) r = fmaxf(yr[j] * scale[d] + shift[d], 0.0f);
        o.u[j] = f2bf(r);
    }
    *(uint4*)(out_bf + (size_t)n * ADIM + d0) = o.v;
}

// ---------------- pooling ----------------
__global__ void pool_kernel(const ushort_t* __restrict__ h_bf,
                            const int* __restrict__ batch,
                            float* __restrict__ pooled,
                            float* __restrict__ counts) {
    int n = blockIdx.x;
    int tid = threadIdx.x;  // 320
    int g = batch[n];
    if (tid == 0) atomicAdd(&counts[g], 1.0f);
    if (tid < DIM)
        atomicAdd(&pooled[(size_t)g * DIM + tid],
                  bf2f(h_bf[(size_t)n * ADIM + tid]));
}

// ---------------- MLP head ----------------
__global__ void mlp1_kernel(const float* __restrict__ pooled,
                            const float* __restrict__ counts,
                            const float* __restrict__ Wc1,
                            const float* __restrict__ bc1,
                            float* __restrict__ hidden) {
    int g = blockIdx.x;
    int j = threadIdx.x;  // 192
    if (j >= DHALF) return;
    float inv = 1.0f / fmaxf(counts[g], 1.0f);
    const float* prow = pooled + (size_t)g * DIM;
    float acc = 0.0f;
    for (int k = 0; k < DIM; ++k) acc += prow[k] * Wc1[k * DHALF + j];
    hidden[g * DHALF + j] = fmaxf(acc * inv + bc1[j], 0.0f);
}

__global__ void mlp2_kernel(const float* __restrict__ hidden,
                            const float* __restrict__ Wc2,
                            const float* __restrict__ bc2,
                            float* __restrict__ out) {
    int idx = blockIdx.x * blockDim.x + threadIdx.x;
    if (idx >= NGRAPH * NCLS) return;
    int g = idx / NCLS;
    int c = idx - g * NCLS;
    const float* hrow = hidden + g * DHALF;
    float acc = bc2[c];
    for (int j = 0; j < DHALF; ++j) acc += hrow[j] * Wc2[j * NCLS + c];
    out[idx] = acc;
}

extern "C" void kernel_launch(void* const* d_in, const int* in_sizes, int n_in,
                              void* d_out, int out_size, void* d_ws, size_t ws_size,
                              hipStream_t stream) {
    const int*   x         = (const int*)d_in[0];
    const int*   edge_index= (const int*)d_in[1];
    const float* edge_attr = (const float*)d_in[2];
    const int*   batch     = (const int*)d_in[3];
    const float* node_emb  = (const float*)d_in[4];
    const float* edge_W    = (const float*)d_in[5];
    const float* edge_b    = (const float*)d_in[6];
    const float* eps       = (const float*)d_in[7];
    const float* W1        = (const float*)d_in[8];
    const float* g1        = (const float*)d_in[10];
    const float* be1       = (const float*)d_in[11];
    const float* W2        = (const float*)d_in[12];
    const float* g2        = (const float*)d_in[14];
    const float* be2       = (const float*)d_in[15];
    const float* Wc1       = (const float*)d_in[16];
    const float* bc1       = (const float*)d_in[17];
    const float* Wc2       = (const float*)d_in[18];
    const float* bc2       = (const float*)d_in[19];
    float* out = (float*)d_out;

    const int* src = edge_index;
    const int* dst = edge_index + N_EDGES;

    // ---- workspace layout (bytes, 64-aligned blocks) ----
    char* w = (char*)d_ws;
    size_t cur_off = 0;
    auto alloc = [&](size_t bytes) {
        char* p = w + cur_off;
        cur_off += (bytes + 63) & ~(size_t)63;
        return p;
    };
    const size_t AROW = (size_t)ROWS_PAD * ADIM;
    ushort_t* h_bf  = (ushort_t*)alloc(AROW * 2);
    ushort_t* zab   = (ushort_t*)alloc(AROW * 2);     // z_bf / a_bf shared
    float*    Ybuf  = (float*)alloc(AROW * 4);
    ushort_t* Wt    = (ushort_t*)alloc((size_t)10 * ADIM * ADIM * 2);
    int*      deg   = (int*)alloc(N_NODES * 4);
    int*      off   = (int*)alloc((N_NODES + 1) * 4);
    int*      curp  = (int*)alloc(N_NODES * 4);
    int*      psrc  = (int*)alloc((size_t)N_EDGES * 4);
    float*    pea   = (float*)alloc((size_t)N_EDGES * 8 * 4);
    float*    colsum= (float*)alloc(ADIM * 4);
    float*    colsq = (float*)alloc(ADIM * 4);
    float*    scale = (float*)alloc(ADIM * 4);
    float*    shift = (float*)alloc(ADIM * 4);
    float*    pooled= (float*)alloc((size_t)NGRAPH * DIM * 4);
    float*    counts= (float*)alloc(NGRAPH * 4);
    float*    hidden= (float*)alloc((size_t)NGRAPH * DHALF * 4);

    // ---- prep ----
    hipMemsetAsync(deg, 0, N_NODES * 4, stream);
    // zero pad rows of zab (rows 20000..20031) once per call
    hipMemsetAsync(zab + (size_t)N_NODES * ADIM, 0,
                   (size_t)(ROWS_PAD - N_NODES) * ADIM * 2, stream);

    node_enc_kernel<<<CDIV(N_NODES * 40, 256), 256, 0, stream>>>(x, node_emb, h_bf);
    wt_prep_kernel<<<CDIV(10 * ADIM * ADIM, 256), 256, 0, stream>>>(W1, W2, Wt);
    deg_kernel<<<CDIV(N_EDGES, 256), 256, 0, stream>>>(dst, deg);
    scan_kernel<<<1, 1024, 0, stream>>>(deg, off, curp);
    scatter_kernel<<<CDIV(N_EDGES, 256), 256, 0, stream>>>(src, dst, edge_attr,
                                                           curp, psrc, pea);

    dim3 ggrid(ROWS_PAD / GBM, 2);  // 313 x 2

    for (int i = 0; i < N_LAYERS; ++i) {
        // z_bf = (1+eps)*h + sum relu(h[src]+ea)
        msg_kernel<<<MSG_BLOCKS, 256, 0, stream>>>(h_bf, zab, off, psrc, pea,
                                                   edge_W, edge_b, eps, i);
        // Y = z @ W1
        gemm_kernel<<<ggrid, 256, 0, stream>>>(zab, Wt + (size_t)i * ADIM * ADIM, Ybuf);
        hipMemsetAsync(colsum, 0, 2 * ADIM * 4, stream);  // colsum+colsq adjacent? (separate allocs, 64-pad) -> zero both
        hipMemsetAsync(colsq, 0, ADIM * 4, stream);
        stats_kernel<<<STAT_BLOCKS, ADIM, 0, stream>>>(Ybuf, colsum, colsq);
        scaleshift_kernel<<<2, 256, 0, stream>>>(colsum, colsq, g1 + i * DIM,
                                                 be1 + i * DIM, scale, shift);
        // a_bf = relu(BN(Y))
        apply_bn_kernel<<<CDIV(N_NODES * 40, 256), 256, 0, stream>>>(Ybuf, scale,
                                                                     shift, zab);
        // Y = a @ W2
        gemm_kernel<<<ggrid, 256, 0, stream>>>(zab, Wt + (size_t)(5 + i) * ADIM * ADIM, Ybuf);
        hipMemsetAsync(colsum, 0, ADIM * 4, stream);
        hipMemsetAsync(colsq, 0, ADIM * 4, stream);
        stats_kernel<<<STAT_BLOCKS, ADIM, 0, stream>>>(Ybuf, colsum, colsq);
        scaleshift_kernel<<<2, 256, 0, stream>>>(colsum, colsq, g2 + i * DIM,
                                                 be2 + i * DIM, scale, shift);
        // h_bf = relu(BN(Y))
        apply_bn_kernel<<<CDIV(N_NODES * 40, 256), 256, 0, stream>>>(Ybuf, scale,
                                                                     shift, h_bf);
    }

    // pooling + head
    hipMemsetAsync(pooled, 0, (size_t)NGRAPH * DIM * 4, stream);
    hipMemsetAsync(counts, 0, NGRAPH * 4, stream);
    pool_kernel<<<N_NODES, ADIM, 0, stream>>>(h_bf, batch, pooled, counts);
    mlp1_kernel<<<NGRAPH, 192, 0, stream>>>(pooled, counts, Wc1, bc1, hidden);
    mlp2_kernel<<<CDIV(NGRAPH * NCLS, 256), 256, 0, stream>>>(hidden, Wc2, bc2, out);
}

// Round 3
// 1140.199 us; speedup vs baseline: 3.3351x; 1.2255x over previous
//
#include <hip/hip_runtime.h>
#include <hip/hip_bf16.h>
#include <stdint.h>

#define N_NODES 20000
#define N_EDGES 320000
#define DIM 300
#define ADIM 320              // padded activation stride (cols 300..319 = 0)
#define ROWS_PAD 20096        // 157 * 128
#define N_LAYERS 5
#define EDIM 7
#define NGRAPH 128
#define NCLS 6
#define DHALF 150
#define BN_EPS 1e-5f

#define CDIV(a, b) (((a) + (b) - 1) / (b))

typedef short bf16x8 __attribute__((ext_vector_type(8)));
typedef float f32x4 __attribute__((ext_vector_type(4)));
typedef unsigned short ushort_t;

__device__ __forceinline__ float bf2f(ushort_t u) {
    union { float f; uint32_t i; } v; v.i = ((uint32_t)u) << 16; return v.f;
}
__device__ __forceinline__ ushort_t f2bf(float f) {
    union { float f; uint32_t i; } v; v.f = f;
    uint32_t x = v.i;
    x += 0x7FFFu + ((x >> 16) & 1u);   // RTN-even (no inf/nan expected)
    return (ushort_t)(x >> 16);
}

// ---------------- node encoder: h_bf[n][d] = bf16(node_emb[x[n]][d]) --------
__global__ void node_enc_kernel(const int* __restrict__ x,
                                const float* __restrict__ node_emb,
                                ushort_t* __restrict__ h_bf) {
    int idx = blockIdx.x * blockDim.x + threadIdx.x;  // 20000*40
    if (idx >= N_NODES * 40) return;
    int n = idx / 40;
    int d0 = (idx - n * 40) * 8;
    const float* src = node_emb + (size_t)x[n] * DIM;
    union { ushort_t u[8]; uint4 v; } o;
#pragma unroll
    for (int j = 0; j < 8; ++j) {
        int d = d0 + j;
        o.u[j] = (d < DIM) ? f2bf(src[d]) : (ushort_t)0;
    }
    *(uint4*)(h_bf + (size_t)n * ADIM + d0) = o.v;
}

// ---------------- W transpose+convert: Wt[mat][n][k] = bf16(W[k][n]) --------
__global__ void wt_prep_kernel(const float* __restrict__ W1,
                               const float* __restrict__ W2,
                               ushort_t* __restrict__ Wt) {
    int idx = blockIdx.x * blockDim.x + threadIdx.x;  // 10*320*320
    if (idx >= 10 * ADIM * ADIM) return;
    int mat = idx / (ADIM * ADIM);
    int rem = idx - mat * ADIM * ADIM;
    int k = rem / ADIM;
    int n = rem - k * ADIM;
    const float* src = (mat < 5) ? (W1 + (size_t)mat * DIM * DIM)
                                 : (W2 + (size_t)(mat - 5) * DIM * DIM);
    float v = (k < DIM && n < DIM) ? src[(size_t)k * DIM + n] : 0.0f;
    Wt[(size_t)mat * ADIM * ADIM + (size_t)n * ADIM + k] = f2bf(v);
}

// ---------------- CSR build ----------------
__global__ void deg_kernel(const int* __restrict__ dst, int* __restrict__ deg) {
    int e = blockIdx.x * blockDim.x + threadIdx.x;
    if (e < N_EDGES) atomicAdd(&deg[dst[e]], 1);
}

__global__ void scan_kernel(const int* __restrict__ deg, int* __restrict__ off,
                            int* __restrict__ cur) {
    __shared__ int sh[1024];
    int t = threadIdx.x;
    int base = t * 20;
    int local[20];
    int s = 0;
#pragma unroll
    for (int j = 0; j < 20; ++j) {
        int i = base + j;
        int v = (i < N_NODES) ? deg[i] : 0;
        local[j] = v;
        s += v;
    }
    sh[t] = s;
    __syncthreads();
    for (int o = 1; o < 1024; o <<= 1) {
        int v = sh[t];
        int add = (t >= o) ? sh[t - o] : 0;
        __syncthreads();
        sh[t] = v + add;
        __syncthreads();
    }
    int run = (t > 0) ? sh[t - 1] : 0;
#pragma unroll
    for (int j = 0; j < 20; ++j) {
        int i = base + j;
        if (i < N_NODES) {
            off[i] = run;
            cur[i] = run;
            run += local[j];
        }
    }
    if (t == 1023) off[N_NODES] = sh[1023];
}

__global__ void scatter_kernel(const int* __restrict__ src,
                               const int* __restrict__ dst,
                               const float* __restrict__ edge_attr,
                               int* __restrict__ cur,
                               int* __restrict__ perm_src,
                               float* __restrict__ perm_ea) {
    int e = blockIdx.x * blockDim.x + threadIdx.x;
    if (e >= N_EDGES) return;
    int d = dst[e];
    int p = atomicAdd(&cur[d], 1);
    perm_src[p] = src[e];
    const float* ar = edge_attr + (size_t)e * EDIM;
    float* pr = perm_ea + (size_t)p * 8;
#pragma unroll
    for (int j = 0; j < EDIM; ++j) pr[j] = ar[j];
    pr[7] = 0.0f;
}

// ------- CSR message+aggregate+combine, 2-deep software pipeline -------------
#define MSG_BLOCKS 768
#define MSG_WAVES (MSG_BLOCKS * 4)
__global__ __launch_bounds__(256) void msg_kernel(
    const ushort_t* __restrict__ h_bf, ushort_t* __restrict__ z_bf,
    const int* __restrict__ off, const int* __restrict__ perm_src,
    const float* __restrict__ perm_ea, const float* __restrict__ edge_W,
    const float* __restrict__ edge_b, const float* __restrict__ eps, int layer) {
    int gw = (blockIdx.x * 256 + threadIdx.x) >> 6;
    int lane = threadIdx.x & 63;

    float ew[5][7], eb[5];
#pragma unroll
    for (int c = 0; c < 5; ++c) {
        int d = c * 64 + lane;
        bool ok = (d < DIM);
        eb[c] = ok ? edge_b[d] : 0.0f;
#pragma unroll
        for (int j = 0; j < EDIM; ++j)
            ew[c][j] = ok ? edge_W[j * DIM + d] : 0.0f;
    }
    float epsv = 1.0f + eps[layer];

    for (int n = gw; n < N_NODES; n += MSG_WAVES) {
        int p0 = off[n], p1 = off[n + 1];
        float acc[5] = {0.f, 0.f, 0.f, 0.f, 0.f};
        float4 na03, na47;
        float nhv[5];
        int s2i = 0;
        if (p0 < p1) {
            int s1i = perm_src[p0];
            const float* ap = perm_ea + (size_t)p0 * 8;
            na03 = *(const float4*)ap;
            na47 = *(const float4*)(ap + 4);
            const ushort_t* hr = h_bf + (size_t)s1i * ADIM;
#pragma unroll
            for (int c = 0; c < 5; ++c) nhv[c] = bf2f(hr[c * 64 + lane]);
            if (p0 + 1 < p1) s2i = perm_src[p0 + 1];
        }
        for (int p = p0; p < p1; ++p) {
            float4 ca03 = na03, ca47 = na47;
            float chv[5];
#pragma unroll
            for (int c = 0; c < 5; ++c) chv[c] = nhv[c];
            if (p + 1 < p1) {
                const float* ap = perm_ea + (size_t)(p + 1) * 8;
                na03 = *(const float4*)ap;
                na47 = *(const float4*)(ap + 4);
                const ushort_t* hr = h_bf + (size_t)s2i * ADIM;
#pragma unroll
                for (int c = 0; c < 5; ++c) nhv[c] = bf2f(hr[c * 64 + lane]);
                if (p + 2 < p1) s2i = perm_src[p + 2];
            }
#pragma unroll
            for (int c = 0; c < 5; ++c) {
                float ea = eb[c];
                ea += ca03.x * ew[c][0];
                ea += ca03.y * ew[c][1];
                ea += ca03.z * ew[c][2];
                ea += ca03.w * ew[c][3];
                ea += ca47.x * ew[c][4];
                ea += ca47.y * ew[c][5];
                ea += ca47.z * ew[c][6];
                acc[c] += fmaxf(chv[c] + ea, 0.0f);
            }
        }
        const ushort_t* hn = h_bf + (size_t)n * ADIM;
        ushort_t* zr = z_bf + (size_t)n * ADIM;
#pragma unroll
        for (int c = 0; c < 5; ++c) {
            int d = c * 64 + lane;
            float z = epsv * bf2f(hn[d]) + acc[c];
            zr[d] = f2bf(z);
        }
    }
}

// ---------------- bf16 MFMA GEMM + fused BN stats ----------------------------
// A: [ROWS_PAD][320] bf16 (pads zero). Wt: [320][320] bf16, Wt[n][k].
// Y: f32, rows<20000 cols<300 written. s1/s2: column sum / sumsq (atomic).
// Block 128x160, 4 waves (2M x 2N), wave tile 64x80, K-step 64.
#define GBM 128
#define GBN 160
__device__ __forceinline__ int swz(int row, int k8) {
    return ((row << 7) + (k8 << 4)) ^ ((row & 7) << 4);
}

__global__ __launch_bounds__(256) void gemm_kernel(
    const ushort_t* __restrict__ A, const ushort_t* __restrict__ Wt,
    float* __restrict__ Y, float* __restrict__ gs1, float* __restrict__ gs2) {
    __shared__ ushort_t sA[GBM * 64];   // 16 KB, swizzled
    __shared__ ushort_t sB[GBN * 64];   // 20 KB, swizzled
    char* sAc = (char*)sA;
    char* sBc = (char*)sB;

    int tid = threadIdx.x;
    int lane = tid & 63;
    int wv = tid >> 6;
    int wm = wv & 1;        // 64-row half
    int wn = wv >> 1;       // 80-col half
    int brow = blockIdx.x * GBM;
    int bcol = blockIdx.y * GBN;

    f32x4 acc[4][5];
#pragma unroll
    for (int m = 0; m < 4; ++m)
#pragma unroll
        for (int n = 0; n < 5; ++n) acc[m][n] = (f32x4){0.f, 0.f, 0.f, 0.f};

    int l15 = lane & 15, l4 = lane >> 4;

    for (int kt = 0; kt < 5; ++kt) {
        int k0 = kt * 64;
        // stage A: 128x64 -> 1024 16B chunks, 4/thread
#pragma unroll
        for (int it = 0; it < 4; ++it) {
            int idx = tid + it * 256;
            int row = idx >> 3, k8 = idx & 7;
            const ushort_t* g = A + (size_t)(brow + row) * ADIM + k0 + k8 * 8;
            *(uint4*)(sAc + swz(row, k8)) = *(const uint4*)g;
        }
        // stage B: 160x64 -> 1280 chunks, 5/thread
#pragma unroll
        for (int it = 0; it < 5; ++it) {
            int idx = tid + it * 256;
            int row = idx >> 3, k8 = idx & 7;
            const ushort_t* g = Wt + (size_t)(bcol + row) * ADIM + k0 + k8 * 8;
            *(uint4*)(sBc + swz(row, k8)) = *(const uint4*)g;
        }
        __syncthreads();

#pragma unroll
        for (int kk = 0; kk < 2; ++kk) {
            bf16x8 a[4], b[5];
#pragma unroll
            for (int m = 0; m < 4; ++m)
                a[m] = *(const bf16x8*)(sAc + swz(wm * 64 + m * 16 + l15, kk * 4 + l4));
#pragma unroll
            for (int n = 0; n < 5; ++n)
                b[n] = *(const bf16x8*)(sBc + swz(wn * 80 + n * 16 + l15, kk * 4 + l4));
#pragma unroll
            for (int m = 0; m < 4; ++m)
#pragma unroll
                for (int n = 0; n < 5; ++n)
                    acc[m][n] = __builtin_amdgcn_mfma_f32_16x16x32_bf16(
                        a[m], b[n], acc[m][n], 0, 0, 0);
        }
        __syncthreads();
    }

    // ---- write Y + fused column stats ----
#pragma unroll
    for (int n = 0; n < 5; ++n) {
        int col = bcol + wn * 80 + n * 16 + l15;
        float s1 = 0.f, s2 = 0.f;
#pragma unroll
        for (int m = 0; m < 4; ++m) {
#pragma unroll
            for (int r = 0; r < 4; ++r) {
                int row = brow + wm * 64 + m * 16 + l4 * 4 + r;
                float v = acc[m][n][r];
                bool ok = (row < N_NODES) && (col < DIM);
                if (ok) {
                    Y[(size_t)row * ADIM + col] = v;
                    s1 += v;
                    s2 += v * v;
                }
            }
        }
        s1 += __shfl_xor(s1, 16, 64);
        s1 += __shfl_xor(s1, 32, 64);
        s2 += __shfl_xor(s2, 16, 64);
        s2 += __shfl_xor(s2, 32, 64);
        if (l4 == 0 && col < DIM) {
            atomicAdd(&gs1[col], s1);
            atomicAdd(&gs2[col], s2);
        }
    }
}

// ---------------- scale/shift from stats (zeroes stats for next use) --------
__global__ void scaleshift_kernel(float* __restrict__ s1,
                                  float* __restrict__ s2,
                                  const float* __restrict__ g,
                                  const float* __restrict__ be,
                                  float* __restrict__ scale,
                                  float* __restrict__ shift) {
    int d = blockIdx.x * blockDim.x + threadIdx.x;
    if (d >= ADIM) return;
    if (d < DIM) {
        const float invn = 1.0f / (float)N_NODES;
        float mean = s1[d] * invn;
        float var = s2[d] * invn - mean * mean;
        float sc = g[d] * rsqrtf(var + BN_EPS);
        scale[d] = sc;
        shift[d] = be[d] - mean * sc;
    }
    s1[d] = 0.0f;
    s2[d] = 0.0f;
}

// ---------------- out_bf = bf16(relu(y*scale+shift)), cols>=300 -> 0 --------
__global__ void apply_bn_kernel(const float* __restrict__ y,
                                const float* __restrict__ scale,
                                const float* __restrict__ shift,
                                ushort_t* __restrict__ out_bf) {
    int idx = blockIdx.x * blockDim.x + threadIdx.x;  // 20000*40
    if (idx >= N_NODES * 40) return;
    int n = idx / 40;
    int d0 = (idx - n * 40) * 8;
    const float* yr = y + (size_t)n * ADIM + d0;
    union { ushort_t u[8]; uint4 v; } o;
#pragma unroll
    for (int j = 0; j < 8; ++j) {
        int d = d0 + j;
        float r = 0.0f;
        if (d < DIM) r = fmaxf(yr[j] * scale[d] + shift[d], 0.0f);
        o.u[j] = f2bf(r);
    }
    *(uint4*)(out_bf + (size_t)n * ADIM + d0) = o.v;
}

// ---------------- pooling: sorted batch -> segmented reduction --------------
__device__ __forceinline__ int lbound(const int* __restrict__ batch, int g) {
    int lo = 0, hi = N_NODES;
    while (lo < hi) {
        int mid = (lo + hi) >> 1;
        if (batch[mid] < g) lo = mid + 1; else hi = mid;
    }
    return lo;
}

__global__ void pool_kernel(const ushort_t* __restrict__ h_bf,
                            const int* __restrict__ batch,
                            float* __restrict__ pooled,
                            float* __restrict__ counts) {
    int g = blockIdx.x;
    int chunk = blockIdx.y;   // 0..3
    int d = threadIdx.x;      // 320
    int s = lbound(batch, g);
    int e = lbound(batch, g + 1);
    if (chunk == 0 && d == 0) counts[g] = (float)(e - s);
    if (d >= DIM) return;
    int len = e - s;
    int per = (len + 3) >> 2;
    int r0 = s + chunk * per;
    int r1 = min(r0 + per, e);
    float a = 0.f;
    for (int r = r0; r < r1; ++r) a += bf2f(h_bf[(size_t)r * ADIM + d]);
    if (r1 > r0) atomicAdd(&pooled[(size_t)g * DIM + d], a);
}

// ---------------- MLP head ----------------
__global__ void mlp1_kernel(const float* __restrict__ pooled,
                            const float* __restrict__ counts,
                            const float* __restrict__ Wc1,
                            const float* __restrict__ bc1,
                            float* __restrict__ hidden) {
    int g = blockIdx.x;
    int j = threadIdx.x;  // 192
    if (j >= DHALF) return;
    float inv = 1.0f / fmaxf(counts[g], 1.0f);
    const float* prow = pooled + (size_t)g * DIM;
    float acc = 0.0f;
    for (int k = 0; k < DIM; ++k) acc += prow[k] * Wc1[k * DHALF + j];
    hidden[g * DHALF + j] = fmaxf(acc * inv + bc1[j], 0.0f);
}

__global__ void mlp2_kernel(const float* __restrict__ hidden,
                            const float* __restrict__ Wc2,
                            const float* __restrict__ bc2,
                            float* __restrict__ out) {
    int idx = blockIdx.x * blockDim.x + threadIdx.x;
    if (idx >= NGRAPH * NCLS) return;
    int g = idx / NCLS;
    int c = idx - g * NCLS;
    const float* hrow = hidden + g * DHALF;
    float acc = bc2[c];
    for (int j = 0; j < DHALF; ++j) acc += hrow[j] * Wc2[j * NCLS + c];
    out[idx] = acc;
}

extern "C" void kernel_launch(void* const* d_in, const int* in_sizes, int n_in,
                              void* d_out, int out_size, void* d_ws, size_t ws_size,
                              hipStream_t stream) {
    const int*   x         = (const int*)d_in[0];
    const int*   edge_index= (const int*)d_in[1];
    const float* edge_attr = (const float*)d_in[2];
    const int*   batch     = (const int*)d_in[3];
    const float* node_emb  = (const float*)d_in[4];
    const float* edge_W    = (const float*)d_in[5];
    const float* edge_b    = (const float*)d_in[6];
    const float* eps       = (const float*)d_in[7];
    const float* W1        = (const float*)d_in[8];
    const float* g1        = (const float*)d_in[10];
    const float* be1       = (const float*)d_in[11];
    const float* W2        = (const float*)d_in[12];
    const float* g2        = (const float*)d_in[14];
    const float* be2       = (const float*)d_in[15];
    const float* Wc1       = (const float*)d_in[16];
    const float* bc1       = (const float*)d_in[17];
    const float* Wc2       = (const float*)d_in[18];
    const float* bc2       = (const float*)d_in[19];
    float* out = (float*)d_out;

    const int* src = edge_index;
    const int* dst = edge_index + N_EDGES;

    char* w = (char*)d_ws;
    size_t cur_off = 0;
    auto alloc = [&](size_t bytes) {
        char* p = w + cur_off;
        cur_off += (bytes + 63) & ~(size_t)63;
        return p;
    };
    const size_t AROW = (size_t)ROWS_PAD * ADIM;
    ushort_t* h_bf  = (ushort_t*)alloc(AROW * 2);
    ushort_t* zab   = (ushort_t*)alloc(AROW * 2);     // z_bf / a_bf shared
    float*    Ybuf  = (float*)alloc(AROW * 4);
    ushort_t* Wt    = (ushort_t*)alloc((size_t)10 * ADIM * ADIM * 2);
    int*      deg   = (int*)alloc(N_NODES * 4);
    int*      off   = (int*)alloc((N_NODES + 1) * 4);
    int*      curp  = (int*)alloc(N_NODES * 4);
    int*      psrc  = (int*)alloc((size_t)N_EDGES * 4);
    float*    pea   = (float*)alloc((size_t)N_EDGES * 8 * 4);
    float*    colsum= (float*)alloc(ADIM * 4);
    float*    colsq = (float*)alloc(ADIM * 4);
    float*    scale = (float*)alloc(ADIM * 4);
    float*    shift = (float*)alloc(ADIM * 4);
    float*    pooled= (float*)alloc((size_t)NGRAPH * DIM * 4);
    float*    counts= (float*)alloc(NGRAPH * 4);
    float*    hidden= (float*)alloc((size_t)NGRAPH * DHALF * 4);

    // ---- prep ----
    hipMemsetAsync(deg, 0, N_NODES * 4, stream);
    hipMemsetAsync(zab + (size_t)N_NODES * ADIM, 0,
                   (size_t)(ROWS_PAD - N_NODES) * ADIM * 2, stream);
    hipMemsetAsync(colsum, 0, ADIM * 4, stream);
    hipMemsetAsync(colsq, 0, ADIM * 4, stream);

    node_enc_kernel<<<CDIV(N_NODES * 40, 256), 256, 0, stream>>>(x, node_emb, h_bf);
    wt_prep_kernel<<<CDIV(10 * ADIM * ADIM, 256), 256, 0, stream>>>(W1, W2, Wt);
    deg_kernel<<<CDIV(N_EDGES, 256), 256, 0, stream>>>(dst, deg);
    scan_kernel<<<1, 1024, 0, stream>>>(deg, off, curp);
    scatter_kernel<<<CDIV(N_EDGES, 256), 256, 0, stream>>>(src, dst, edge_attr,
                                                           curp, psrc, pea);

    dim3 ggrid(ROWS_PAD / GBM, 2);  // 157 x 2

    for (int i = 0; i < N_LAYERS; ++i) {
        msg_kernel<<<MSG_BLOCKS, 256, 0, stream>>>(h_bf, zab, off, psrc, pea,
                                                   edge_W, edge_b, eps, i);
        gemm_kernel<<<ggrid, 256, 0, stream>>>(zab, Wt + (size_t)i * ADIM * ADIM,
                                               Ybuf, colsum, colsq);
        scaleshift_kernel<<<2, 256, 0, stream>>>(colsum, colsq, g1 + i * DIM,
                                                 be1 + i * DIM, scale, shift);
        apply_bn_kernel<<<CDIV(N_NODES * 40, 256), 256, 0, stream>>>(Ybuf, scale,
                                                                     shift, zab);
        gemm_kernel<<<ggrid, 256, 0, stream>>>(zab, Wt + (size_t)(5 + i) * ADIM * ADIM,
                                               Ybuf, colsum, colsq);
        scaleshift_kernel<<<2, 256, 0, stream>>>(colsum, colsq, g2 + i * DIM,
                                                 be2 + i * DIM, scale, shift);
        apply_bn_kernel<<<CDIV(N_NODES * 40, 256), 256, 0, stream>>>(Ybuf, scale,
                                                                     shift, h_bf);
    }

    hipMemsetAsync(pooled, 0, (size_t)NGRAPH * DIM * 4, stream);
    dim3 pgrid(NGRAPH, 4);
    pool_kernel<<<pgrid, ADIM, 0, stream>>>(h_bf, batch, pooled, counts);
    mlp1_kernel<<<NGRAPH, 192, 0, stream>>>(pooled, counts, Wc1, bc1, hidden);
    mlp2_kernel<<<CDIV(NGRAPH * NCLS, 256), 256, 0, stream>>>(hidden, Wc2, bc2, out);
}

// Round 4
// 980.291 us; speedup vs baseline: 3.8791x; 1.1631x over previous
//
#include <hip/hip_runtime.h>
#include <hip/hip_bf16.h>
#include <stdint.h>

#define N_NODES 20000
#define N_EDGES 320000
#define DIM 300
#define ADIM 320              // padded activation stride (cols 300..319 = 0)
#define ROWS_PAD 20096        // 157 * 128
#define N_LAYERS 5
#define EDIM 7
#define NGRAPH 128
#define NCLS 6
#define DHALF 150
#define BN_EPS 1e-5f

#define CDIV(a, b) (((a) + (b) - 1) / (b))

typedef short bf16x8 __attribute__((ext_vector_type(8)));
typedef float f32x4 __attribute__((ext_vector_type(4)));
typedef unsigned short ushort_t;

__device__ __forceinline__ float bf2f(ushort_t u) {
    union { float f; uint32_t i; } v; v.i = ((uint32_t)u) << 16; return v.f;
}
__device__ __forceinline__ ushort_t f2bf(float f) {
    union { float f; uint32_t i; } v; v.f = f;
    uint32_t x = v.i;
    x += 0x7FFFu + ((x >> 16) & 1u);   // RTN-even (no inf/nan expected)
    return (ushort_t)(x >> 16);
}

// ---------------- node encoder: h_bf[n][d] = bf16(node_emb[x[n]][d]) --------
__global__ void node_enc_kernel(const int* __restrict__ x,
                                const float* __restrict__ node_emb,
                                ushort_t* __restrict__ h_bf) {
    int idx = blockIdx.x * blockDim.x + threadIdx.x;  // 20000*40
    if (idx >= N_NODES * 40) return;
    int n = idx / 40;
    int d0 = (idx - n * 40) * 8;
    const float* src = node_emb + (size_t)x[n] * DIM;
    union { ushort_t u[8]; uint4 v; } o;
#pragma unroll
    for (int j = 0; j < 8; ++j) {
        int d = d0 + j;
        o.u[j] = (d < DIM) ? f2bf(src[d]) : (ushort_t)0;
    }
    *(uint4*)(h_bf + (size_t)n * ADIM + d0) = o.v;
}

// ---------------- W transpose+convert: Wt[mat][n][k] = bf16(W[k][n]) --------
__global__ void wt_prep_kernel(const float* __restrict__ W1,
                               const float* __restrict__ W2,
                               ushort_t* __restrict__ Wt) {
    int idx = blockIdx.x * blockDim.x + threadIdx.x;  // 10*320*320
    if (idx >= 10 * ADIM * ADIM) return;
    int mat = idx / (ADIM * ADIM);
    int rem = idx - mat * ADIM * ADIM;
    int k = rem / ADIM;
    int n = rem - k * ADIM;
    const float* src = (mat < 5) ? (W1 + (size_t)mat * DIM * DIM)
                                 : (W2 + (size_t)(mat - 5) * DIM * DIM);
    float v = (k < DIM && n < DIM) ? src[(size_t)k * DIM + n] : 0.0f;
    Wt[(size_t)mat * ADIM * ADIM + (size_t)n * ADIM + k] = f2bf(v);
}

// ---------------- CSR build ----------------
__global__ void deg_kernel(const int* __restrict__ dst, int* __restrict__ deg) {
    int e = blockIdx.x * blockDim.x + threadIdx.x;
    if (e < N_EDGES) atomicAdd(&deg[dst[e]], 1);
}

__global__ void scan_kernel(const int* __restrict__ deg, int* __restrict__ off,
                            int* __restrict__ cur) {
    __shared__ int sh[1024];
    int t = threadIdx.x;
    int base = t * 20;
    int local[20];
    int s = 0;
#pragma unroll
    for (int j = 0; j < 20; ++j) {
        int i = base + j;
        int v = (i < N_NODES) ? deg[i] : 0;
        local[j] = v;
        s += v;
    }
    sh[t] = s;
    __syncthreads();
    for (int o = 1; o < 1024; o <<= 1) {
        int v = sh[t];
        int add = (t >= o) ? sh[t - o] : 0;
        __syncthreads();
        sh[t] = v + add;
        __syncthreads();
    }
    int run = (t > 0) ? sh[t - 1] : 0;
#pragma unroll
    for (int j = 0; j < 20; ++j) {
        int i = base + j;
        if (i < N_NODES) {
            off[i] = run;
            cur[i] = run;
            run += local[j];
        }
    }
    if (t == 1023) off[N_NODES] = sh[1023];
}

__global__ void scatter_kernel(const int* __restrict__ src,
                               const int* __restrict__ dst,
                               const float* __restrict__ edge_attr,
                               int* __restrict__ cur,
                               int* __restrict__ perm_src,
                               float* __restrict__ perm_ea) {
    int e = blockIdx.x * blockDim.x + threadIdx.x;
    if (e >= N_EDGES) return;
    int d = dst[e];
    int p = atomicAdd(&cur[d], 1);
    perm_src[p] = src[e];
    const float* ar = edge_attr + (size_t)e * EDIM;
    float* pr = perm_ea + (size_t)p * 8;
#pragma unroll
    for (int j = 0; j < EDIM; ++j) pr[j] = ar[j];
    pr[7] = 0.0f;
}

// ------- one node per wave: z = (1+eps)*h + sum relu(h[src]+ea) --------------
// block 0 also zeroes the BN stat accumulators for this layer.
#define MSG_BLOCKS 5000
__global__ __launch_bounds__(256) void msg_kernel(
    const ushort_t* __restrict__ h_bf, ushort_t* __restrict__ z_bf,
    const int* __restrict__ off, const int* __restrict__ perm_src,
    const float* __restrict__ perm_ea, const float* __restrict__ edge_W,
    const float* __restrict__ edge_b, const float* __restrict__ eps, int layer,
    float* __restrict__ s1a, float* __restrict__ s2a,
    float* __restrict__ s1b, float* __restrict__ s2b) {
    if (blockIdx.x == 0) {
        for (int d = threadIdx.x; d < ADIM; d += 256) {
            s1a[d] = 0.f; s2a[d] = 0.f; s1b[d] = 0.f; s2b[d] = 0.f;
        }
    }
    int n = (blockIdx.x * 256 + threadIdx.x) >> 6;
    if (n >= N_NODES) return;
    int lane = threadIdx.x & 63;

    float ew[5][7], eb[5];
#pragma unroll
    for (int c = 0; c < 5; ++c) {
        int d = c * 64 + lane;
        bool ok = (d < DIM);
        eb[c] = ok ? edge_b[d] : 0.0f;
#pragma unroll
        for (int j = 0; j < EDIM; ++j)
            ew[c][j] = ok ? edge_W[j * DIM + d] : 0.0f;
    }
    float epsv = 1.0f + eps[layer];

    int p0 = off[n], p1 = off[n + 1];
    float acc[5] = {0.f, 0.f, 0.f, 0.f, 0.f};
    float4 na03, na47;
    float nhv[5];
    int s2i = 0;
    if (p0 < p1) {
        int s1i = perm_src[p0];
        const float* ap = perm_ea + (size_t)p0 * 8;
        na03 = *(const float4*)ap;
        na47 = *(const float4*)(ap + 4);
        const ushort_t* hr = h_bf + (size_t)s1i * ADIM;
#pragma unroll
        for (int c = 0; c < 5; ++c) nhv[c] = bf2f(hr[c * 64 + lane]);
        if (p0 + 1 < p1) s2i = perm_src[p0 + 1];
    }
    for (int p = p0; p < p1; ++p) {
        float4 ca03 = na03, ca47 = na47;
        float chv[5];
#pragma unroll
        for (int c = 0; c < 5; ++c) chv[c] = nhv[c];
        if (p + 1 < p1) {
            const float* ap = perm_ea + (size_t)(p + 1) * 8;
            na03 = *(const float4*)ap;
            na47 = *(const float4*)(ap + 4);
            const ushort_t* hr = h_bf + (size_t)s2i * ADIM;
#pragma unroll
            for (int c = 0; c < 5; ++c) nhv[c] = bf2f(hr[c * 64 + lane]);
            if (p + 2 < p1) s2i = perm_src[p + 2];
        }
#pragma unroll
        for (int c = 0; c < 5; ++c) {
            float ea = eb[c];
            ea += ca03.x * ew[c][0];
            ea += ca03.y * ew[c][1];
            ea += ca03.z * ew[c][2];
            ea += ca03.w * ew[c][3];
            ea += ca47.x * ew[c][4];
            ea += ca47.y * ew[c][5];
            ea += ca47.z * ew[c][6];
            acc[c] += fmaxf(chv[c] + ea, 0.0f);
        }
    }
    const ushort_t* hn = h_bf + (size_t)n * ADIM;
    ushort_t* zr = z_bf + (size_t)n * ADIM;
#pragma unroll
    for (int c = 0; c < 5; ++c) {
        int d = c * 64 + lane;
        float z = epsv * bf2f(hn[d]) + acc[c];
        zr[d] = f2bf(z);
    }
}

// ---------------- bf16 MFMA GEMM + fused BN stats (+optional fused BN on A) --
// Block 128x80, 4 waves (wave tile 32x80), K-step 64, grid 157x4 = 628 blocks.
// BNA=false: A = Abf (bf16 [ROWS_PAD][ADIM]).
// BNA=true:  A = relu(BN(Af32)) via raw sums in_s1/in_s2 + gamma/beta, staged
//            on the fly (NaN/poison in pad rows is squashed by fmaxf).
// Epilogue: Y f32 (rows<20000, cols<300) + per-column sum/sumsq -> gs1/gs2.
__device__ __forceinline__ int swz(int row, int k8) {
    return ((row << 7) + (k8 << 4)) ^ ((row & 7) << 4);
}

template <bool BNA>
__global__ __launch_bounds__(256) void gemm_kernel(
    const ushort_t* __restrict__ Abf, const float* __restrict__ Af32,
    const ushort_t* __restrict__ Wt, float* __restrict__ Y,
    const float* __restrict__ in_s1, const float* __restrict__ in_s2,
    const float* __restrict__ bn_g, const float* __restrict__ bn_be,
    float* __restrict__ gs1, float* __restrict__ gs2) {
    __shared__ ushort_t sA[128 * 64];   // 16 KB, swizzled
    __shared__ ushort_t sB[80 * 64];    // 10 KB, swizzled
    __shared__ float sRed[4 * 160];     // stats cross-wave reduce
    __shared__ float s_scale[ADIM], s_shift[ADIM];
    char* sAc = (char*)sA;
    char* sBc = (char*)sB;

    int tid = threadIdx.x;
    int lane = tid & 63;
    int wv = tid >> 6;                  // wave -> 32-row strip
    int row0 = blockIdx.x * 128;
    int col0 = blockIdx.y * 80;
    int l15 = lane & 15, l4 = lane >> 4;

    if (BNA) {
        for (int d = tid; d < ADIM; d += 256) {
            float sc = 0.f, sh = 0.f;
            if (d < DIM) {
                const float invn = 1.0f / (float)N_NODES;
                float mean = in_s1[d] * invn;
                float var = in_s2[d] * invn - mean * mean;
                sc = bn_g[d] * rsqrtf(var + BN_EPS);
                sh = bn_be[d] - mean * sc;
            }
            s_scale[d] = sc;
            s_shift[d] = sh;
        }
        __syncthreads();
    }

    f32x4 acc[2][5];
#pragma unroll
    for (int m = 0; m < 2; ++m)
#pragma unroll
        for (int n = 0; n < 5; ++n) acc[m][n] = (f32x4){0.f, 0.f, 0.f, 0.f};

    for (int kt = 0; kt < 5; ++kt) {
        int k0 = kt * 64;
        // stage A: 128x64 -> 1024 16B chunks, 4/thread
#pragma unroll
        for (int it = 0; it < 4; ++it) {
            int idx = tid + it * 256;
            int row = idx >> 3, k8 = idx & 7;
            if (!BNA) {
                const ushort_t* g = Abf + (size_t)(row0 + row) * ADIM + k0 + k8 * 8;
                *(uint4*)(sAc + swz(row, k8)) = *(const uint4*)g;
            } else {
                const float* g = Af32 + (size_t)(row0 + row) * ADIM + k0 + k8 * 8;
                float4 y0 = *(const float4*)g;
                float4 y1 = *(const float4*)(g + 4);
                float yv[8] = {y0.x, y0.y, y0.z, y0.w, y1.x, y1.y, y1.z, y1.w};
                int kb = k0 + k8 * 8;
                union { ushort_t u[8]; uint4 v; } o;
#pragma unroll
                for (int j = 0; j < 8; ++j)
                    o.u[j] = f2bf(fmaxf(yv[j] * s_scale[kb + j] + s_shift[kb + j], 0.0f));
                *(uint4*)(sAc + swz(row, k8)) = o.v;
            }
        }
        // stage B: 80x64 -> 640 chunks
#pragma unroll
        for (int it = 0; it < 3; ++it) {
            int idx = tid + it * 256;
            if (idx < 640) {
                int row = idx >> 3, k8 = idx & 7;
                const ushort_t* g = Wt + (size_t)(col0 + row) * ADIM + k0 + k8 * 8;
                *(uint4*)(sBc + swz(row, k8)) = *(const uint4*)g;
            }
        }
        __syncthreads();

#pragma unroll
        for (int kk = 0; kk < 2; ++kk) {
            bf16x8 a[2], b[5];
#pragma unroll
            for (int m = 0; m < 2; ++m)
                a[m] = *(const bf16x8*)(sAc + swz(wv * 32 + m * 16 + l15, kk * 4 + l4));
#pragma unroll
            for (int n = 0; n < 5; ++n)
                b[n] = *(const bf16x8*)(sBc + swz(n * 16 + l15, kk * 4 + l4));
#pragma unroll
            for (int m = 0; m < 2; ++m)
#pragma unroll
                for (int n = 0; n < 5; ++n)
                    acc[m][n] = __builtin_amdgcn_mfma_f32_16x16x32_bf16(
                        a[m], b[n], acc[m][n], 0, 0, 0);
        }
        __syncthreads();
    }

    // ---- write Y + per-wave column stats ----
#pragma unroll
    for (int n = 0; n < 5; ++n) {
        int col = col0 + n * 16 + l15;
        float s1 = 0.f, s2 = 0.f;
#pragma unroll
        for (int m = 0; m < 2; ++m) {
#pragma unroll
            for (int r = 0; r < 4; ++r) {
                int row = row0 + wv * 32 + m * 16 + l4 * 4 + r;
                float v = acc[m][n][r];
                if (row < N_NODES && col < DIM) {
                    Y[(size_t)row * ADIM + col] = v;
                    s1 += v;
                    s2 += v * v;
                }
            }
        }
        s1 += __shfl_xor(s1, 16, 64);
        s1 += __shfl_xor(s1, 32, 64);
        s2 += __shfl_xor(s2, 16, 64);
        s2 += __shfl_xor(s2, 32, 64);
        if (l4 == 0) {
            sRed[wv * 160 + n * 16 + l15] = s1;
            sRed[wv * 160 + 80 + n * 16 + l15] = s2;
        }
    }
    __syncthreads();
    if (tid < 160) {
        float v = sRed[tid] + sRed[160 + tid] + sRed[320 + tid] + sRed[480 + tid];
        int cc = (tid < 80) ? tid : tid - 80;
        int col = col0 + cc;
        if (col < DIM) atomicAdd(((tid < 80) ? gs1 : gs2) + col, v);
    }
}

// ------- h_bf = bf16(relu(BN(y))) with scale/shift computed inline ----------
__global__ void apply_bn_kernel(const float* __restrict__ y,
                                const float* __restrict__ s1,
                                const float* __restrict__ s2,
                                const float* __restrict__ g,
                                const float* __restrict__ be,
                                ushort_t* __restrict__ out_bf) {
    int idx = blockIdx.x * blockDim.x + threadIdx.x;  // 20000*40
    if (idx >= N_NODES * 40) return;
    int n = idx / 40;
    int d0 = (idx - n * 40) * 8;
    const float* yr = y + (size_t)n * ADIM + d0;
    const float invn = 1.0f / (float)N_NODES;
    union { ushort_t u[8]; uint4 v; } o;
#pragma unroll
    for (int j = 0; j < 8; ++j) {
        int d = d0 + j;
        float r = 0.0f;
        if (d < DIM) {
            float mean = s1[d] * invn;
            float var = s2[d] * invn - mean * mean;
            float sc = g[d] * rsqrtf(var + BN_EPS);
            float sh = be[d] - mean * sc;
            r = fmaxf(yr[j] * sc + sh, 0.0f);
        }
        o.u[j] = f2bf(r);
    }
    *(uint4*)(out_bf + (size_t)n * ADIM + d0) = o.v;
}

// ---------------- pooling: sorted batch -> segmented reduction --------------
__device__ __forceinline__ int lbound(const int* __restrict__ batch, int g) {
    int lo = 0, hi = N_NODES;
    while (lo < hi) {
        int mid = (lo + hi) >> 1;
        if (batch[mid] < g) lo = mid + 1; else hi = mid;
    }
    return lo;
}

__global__ void pool_kernel(const ushort_t* __restrict__ h_bf,
                            const int* __restrict__ batch,
                            float* __restrict__ pooled,
                            float* __restrict__ counts) {
    int g = blockIdx.x;
    int chunk = blockIdx.y;   // 0..3
    int d = threadIdx.x;      // 320
    int s = lbound(batch, g);
    int e = lbound(batch, g + 1);
    if (chunk == 0 && d == 0) counts[g] = (float)(e - s);
    if (d >= DIM) return;
    int len = e - s;
    int per = (len + 3) >> 2;
    int r0 = s + chunk * per;
    int r1 = min(r0 + per, e);
    float a = 0.f;
    for (int r = r0; r < r1; ++r) a += bf2f(h_bf[(size_t)r * ADIM + d]);
    if (r1 > r0) atomicAdd(&pooled[(size_t)g * DIM + d], a);
}

// ---------------- MLP head ----------------
__global__ void mlp1_kernel(const float* __restrict__ pooled,
                            const float* __restrict__ counts,
                            const float* __restrict__ Wc1,
                            const float* __restrict__ bc1,
                            float* __restrict__ hidden) {
    int g = blockIdx.x;
    int j = threadIdx.x;  // 192
    if (j >= DHALF) return;
    float inv = 1.0f / fmaxf(counts[g], 1.0f);
    const float* prow = pooled + (size_t)g * DIM;
    float acc = 0.0f;
    for (int k = 0; k < DIM; ++k) acc += prow[k] * Wc1[k * DHALF + j];
    hidden[g * DHALF + j] = fmaxf(acc * inv + bc1[j], 0.0f);
}

__global__ void mlp2_kernel(const float* __restrict__ hidden,
                            const float* __restrict__ Wc2,
                            const float* __restrict__ bc2,
                            float* __restrict__ out) {
    int idx = blockIdx.x * blockDim.x + threadIdx.x;
    if (idx >= NGRAPH * NCLS) return;
    int g = idx / NCLS;
    int c = idx - g * NCLS;
    const float* hrow = hidden + g * DHALF;
    float acc = bc2[c];
    for (int j = 0; j < DHALF; ++j) acc += hrow[j] * Wc2[j * NCLS + c];
    out[idx] = acc;
}

extern "C" void kernel_launch(void* const* d_in, const int* in_sizes, int n_in,
                              void* d_out, int out_size, void* d_ws, size_t ws_size,
                              hipStream_t stream) {
    const int*   x         = (const int*)d_in[0];
    const int*   edge_index= (const int*)d_in[1];
    const float* edge_attr = (const float*)d_in[2];
    const int*   batch     = (const int*)d_in[3];
    const float* node_emb  = (const float*)d_in[4];
    const float* edge_W    = (const float*)d_in[5];
    const float* edge_b    = (const float*)d_in[6];
    const float* eps       = (const float*)d_in[7];
    const float* W1        = (const float*)d_in[8];
    const float* g1        = (const float*)d_in[10];
    const float* be1       = (const float*)d_in[11];
    const float* W2        = (const float*)d_in[12];
    const float* g2        = (const float*)d_in[14];
    const float* be2       = (const float*)d_in[15];
    const float* Wc1       = (const float*)d_in[16];
    const float* bc1       = (const float*)d_in[17];
    const float* Wc2       = (const float*)d_in[18];
    const float* bc2       = (const float*)d_in[19];
    float* out = (float*)d_out;

    const int* src = edge_index;
    const int* dst = edge_index + N_EDGES;

    char* w = (char*)d_ws;
    size_t cur_off = 0;
    auto alloc = [&](size_t bytes) {
        char* p = w + cur_off;
        cur_off += (bytes + 63) & ~(size_t)63;
        return p;
    };
    const size_t AROW = (size_t)ROWS_PAD * ADIM;
    ushort_t* h_bf  = (ushort_t*)alloc(AROW * 2);
    ushort_t* zab   = (ushort_t*)alloc(AROW * 2);
    float*    Ybuf  = (float*)alloc(AROW * 4);
    float*    Y2buf = (float*)alloc(AROW * 4);
    ushort_t* Wt    = (ushort_t*)alloc((size_t)10 * ADIM * ADIM * 2);
    int*      deg   = (int*)alloc(N_NODES * 4);
    int*      off   = (int*)alloc((N_NODES + 1) * 4);
    int*      curp  = (int*)alloc(N_NODES * 4);
    int*      psrc  = (int*)alloc((size_t)N_EDGES * 4);
    float*    pea   = (float*)alloc((size_t)N_EDGES * 8 * 4);
    float*    s1a   = (float*)alloc(ADIM * 4);
    float*    s2a   = (float*)alloc(ADIM * 4);
    float*    s1b   = (float*)alloc(ADIM * 4);
    float*    s2b   = (float*)alloc(ADIM * 4);
    float*    pooled= (float*)alloc((size_t)NGRAPH * DIM * 4);
    float*    counts= (float*)alloc(NGRAPH * 4);
    float*    hidden= (float*)alloc((size_t)NGRAPH * DHALF * 4);

    // ---- prep ----
    hipMemsetAsync(deg, 0, N_NODES * 4, stream);
    hipMemsetAsync(zab + (size_t)N_NODES * ADIM, 0,
                   (size_t)(ROWS_PAD - N_NODES) * ADIM * 2, stream);

    node_enc_kernel<<<CDIV(N_NODES * 40, 256), 256, 0, stream>>>(x, node_emb, h_bf);
    wt_prep_kernel<<<CDIV(10 * ADIM * ADIM, 256), 256, 0, stream>>>(W1, W2, Wt);
    deg_kernel<<<CDIV(N_EDGES, 256), 256, 0, stream>>>(dst, deg);
    scan_kernel<<<1, 1024, 0, stream>>>(deg, off, curp);
    scatter_kernel<<<CDIV(N_EDGES, 256), 256, 0, stream>>>(src, dst, edge_attr,
                                                           curp, psrc, pea);

    dim3 ggrid(ROWS_PAD / 128, 4);  // 157 x 4

    for (int i = 0; i < N_LAYERS; ++i) {
        // z = (1+eps)*h + agg; block 0 zeroes stat buffers
        msg_kernel<<<MSG_BLOCKS, 256, 0, stream>>>(h_bf, zab, off, psrc, pea,
                                                   edge_W, edge_b, eps, i,
                                                   s1a, s2a, s1b, s2b);
        // Y = z @ W1, stats -> s1a/s2a
        gemm_kernel<false><<<ggrid, 256, 0, stream>>>(
            zab, nullptr, Wt + (size_t)i * ADIM * ADIM, Ybuf,
            nullptr, nullptr, nullptr, nullptr, s1a, s2a);
        // Y2 = relu(BN1(Y)) @ W2 (BN fused into A staging), stats -> s1b/s2b
        gemm_kernel<true><<<ggrid, 256, 0, stream>>>(
            nullptr, Ybuf, Wt + (size_t)(5 + i) * ADIM * ADIM, Y2buf,
            s1a, s2a, g1 + i * DIM, be1 + i * DIM, s1b, s2b);
        // h = relu(BN2(Y2))
        apply_bn_kernel<<<CDIV(N_NODES * 40, 256), 256, 0, stream>>>(
            Y2buf, s1b, s2b, g2 + i * DIM, be2 + i * DIM, h_bf);
    }

    hipMemsetAsync(pooled, 0, (size_t)NGRAPH * DIM * 4, stream);
    dim3 pgrid(NGRAPH, 4);
    pool_kernel<<<pgrid, ADIM, 0, stream>>>(h_bf, batch, pooled, counts);
    mlp1_kernel<<<NGRAPH, 192, 0, stream>>>(pooled, counts, Wc1, bc1, hidden);
    mlp2_kernel<<<CDIV(NGRAPH * NCLS, 256), 256, 0, stream>>>(hidden, Wc2, bc2, out);
}